// Round 2
// baseline (517.188 us; speedup 1.0000x reference)
//
#include <hip/hip_runtime.h>
#include <math.h>

#define HDIM 2048
#define THREADS 256
#define VEC (HDIM / (THREADS * 4))  // 2 v4f per thread per row
#define COEF_STRIDE 32              // 20 floats used, padded to 128B

typedef float v4f __attribute__((ext_vector_type(4)));

// ---------------- pass 1: per-token coefficients ----------------
// Reads hs[0] row + act row (touch-once), computes the 10 reductions,
// tanh router math, and emits c[4][4] (identity folded) + cc[4] = 20 floats.
__global__ __launch_bounds__(THREADS, 8)
void coef_kernel(const float* __restrict__ hs,     // [4, T, H]
                 const float* __restrict__ act,    // [T, H]
                 const float* __restrict__ rnw,    // [H]
                 const float* __restrict__ mrw,    // [4, H]
                 const float* __restrict__ pw,     // [16, 4]
                 const float* __restrict__ cw,     // [4, 4]
                 float* __restrict__ coefs,        // [T, COEF_STRIDE]
                 int T)
{
    const int t = blockIdx.x;
    const int tid = threadIdx.x;
    const size_t row = (size_t)t * HDIM;

    const v4f* hs0p = (const v4f*)(hs + row);
    const v4f* actp = (const v4f*)(act + row);
    const v4f* wp   = (const v4f*)rnw;
    const v4f* mrp  = (const v4f*)mrw;

    float acc[10];  // [0]=ssq(hs0), [1..4]=dot(hs0*w,mrw[n]), [5]=ssq(act), [6..9]=dot(act*w,mrw[n])
    #pragma unroll
    for (int k = 0; k < 10; ++k) acc[k] = 0.f;

    #pragma unroll
    for (int v = 0; v < VEC; ++v) {
        const int idx = tid + v * THREADS;
        const v4f x  = __builtin_nontemporal_load(hs0p + idx);
        const v4f a  = __builtin_nontemporal_load(actp + idx);
        const v4f ww = wp[idx];
        acc[0] += x.x*x.x + x.y*x.y + x.z*x.z + x.w*x.w;
        acc[5] += a.x*a.x + a.y*a.y + a.z*a.z + a.w*a.w;
        const float xwx = x.x*ww.x, xwy = x.y*ww.y, xwz = x.z*ww.z, xww = x.w*ww.w;
        const float awx = a.x*ww.x, awy = a.y*ww.y, awz = a.z*ww.z, aww = a.w*ww.w;
        #pragma unroll
        for (int n = 0; n < 4; ++n) {
            const v4f r = mrp[n * (HDIM/4) + idx];
            acc[1+n] += xwx*r.x + xwy*r.y + xwz*r.z + xww*r.w;
            acc[6+n] += awx*r.x + awy*r.y + awz*r.z + aww*r.w;
        }
    }

    __shared__ float part[THREADS/64][10];
    const int lane = tid & 63, wv = tid >> 6;
    #pragma unroll
    for (int k = 0; k < 10; ++k) {
        float s = acc[k];
        #pragma unroll
        for (int off = 32; off >= 1; off >>= 1) s += __shfl_down(s, off, 64);
        if (lane == 0) part[wv][k] = s;
    }
    __syncthreads();
    if (tid >= 64) return;           // one wave finishes the tiny math
    float tot[10];
    #pragma unroll
    for (int k = 0; k < 10; ++k)
        tot[k] = part[0][k] + part[1][k] + part[2][k] + part[3][k];

    const float invH = 1.0f / HDIM;
    const float rs0 = rsqrtf(tot[0] * invH + 1e-6f) * invH;
    const float rsA = rsqrtf(tot[5] * invH + 1e-6f) * invH;
    float m0[4], m2[4];
    #pragma unroll
    for (int n = 0; n < 4; ++n) {
        m0[n] = tanhf(tot[1+n] * rs0);
        m2[n] = tanhf(tot[6+n] * rsA);
    }
    float* cf = coefs + (size_t)t * COEF_STRIDE;
    if (tid < 16) {
        const int j = tid >> 2, i = tid & 3;
        const float* p = pw + (j*4 + i) * 4;        // prediction_w[j*N+i, n]
        cf[tid] = p[0]*m0[0] + p[1]*m0[1] + p[2]*m0[2] + p[3]*m0[3]
                + (i == j ? 1.f : 0.f);             // identity folded (pred += hs[j])
    } else if (tid < 20) {
        const int j = tid - 16;
        const float* q = cw + j*4;                  // correction_w[j, n]
        cf[tid] = 1.f + q[0]*m2[0] + q[1]*m2[1] + q[2]*m2[2] + q[3]*m2[3];
    }
}

// ---------------- pass 2: pure streaming combine ----------------
// No barrier, no shuffle, no transcendental: read 5 planes + uniform coefs,
// write 4 planes. Low VGPR -> 6 blocks/CU; should behave like fillBuffer.
__global__ __launch_bounds__(THREADS, 6)
void combine_kernel(const float* __restrict__ hs,     // [4, T, H]
                    const float* __restrict__ act,    // [T, H]
                    const float* __restrict__ scale,  // [H]
                    const float* __restrict__ coefs,  // [T, COEF_STRIDE]
                    float* __restrict__ out,          // [4, T, H]
                    int T)
{
    const int t = blockIdx.x;
    const int tid = threadIdx.x;
    const size_t row   = (size_t)t * HDIM;
    const size_t plane = (size_t)T * HDIM;

    // uniform (blockIdx-derived) address -> scalar loads, broadcast
    const float* cf = coefs + (size_t)t * COEF_STRIDE;
    float c[4][4], cc[4];
    #pragma unroll
    for (int j = 0; j < 4; ++j) {
        #pragma unroll
        for (int i = 0; i < 4; ++i) c[j][i] = cf[j*4 + i];
        cc[j] = cf[16 + j];
    }

    const v4f* h0p = (const v4f*)(hs + row);
    const v4f* h1p = (const v4f*)(hs + plane + row);
    const v4f* h2p = (const v4f*)(hs + 2*plane + row);
    const v4f* h3p = (const v4f*)(hs + 3*plane + row);
    const v4f* actp = (const v4f*)(act + row);
    const v4f* scp  = (const v4f*)scale;
    float* o0 = out + row;
    float* o1 = out + plane + row;
    float* o2 = out + 2*plane + row;
    float* o3 = out + 3*plane + row;

    #pragma unroll
    for (int v = 0; v < VEC; ++v) {
        const int idx = tid + v * THREADS;
        const v4f x0 = __builtin_nontemporal_load(h0p + idx);
        const v4f x1 = __builtin_nontemporal_load(h1p + idx);
        const v4f x2 = __builtin_nontemporal_load(h2p + idx);
        const v4f x3 = __builtin_nontemporal_load(h3p + idx);
        const v4f a  = __builtin_nontemporal_load(actp + idx);
        const v4f sc = scp[idx];
        v4f r0, r1, r2, r3;
        #define COMP(f) { \
            const float p0 = c[0][0]*x0.f + c[0][1]*x1.f + c[0][2]*x2.f + c[0][3]*x3.f; \
            const float p1 = c[1][0]*x0.f + c[1][1]*x1.f + c[1][2]*x2.f + c[1][3]*x3.f; \
            const float p2 = c[2][0]*x0.f + c[2][1]*x1.f + c[2][2]*x2.f + c[2][3]*x3.f; \
            const float p3 = c[3][0]*x0.f + c[3][1]*x1.f + c[3][2]*x2.f + c[3][3]*x3.f; \
            const float inn = a.f - p0; \
            r0.f = (p0 + inn*cc[0]) * sc.f; \
            r1.f = (p1 + inn*cc[1]) * sc.f; \
            r2.f = (p2 + inn*cc[2]) * sc.f; \
            r3.f = (p3 + inn*cc[3]) * sc.f; }
        COMP(x) COMP(y) COMP(z) COMP(w)
        #undef COMP
        __builtin_nontemporal_store(r0, (v4f*)(o0) + idx);
        __builtin_nontemporal_store(r1, (v4f*)(o1) + idx);
        __builtin_nontemporal_store(r2, (v4f*)(o2) + idx);
        __builtin_nontemporal_store(r3, (v4f*)(o3) + idx);
    }
}

// ---------------- fallback: round-0 fused kernel (if ws too small) ----------------
__global__ __launch_bounds__(THREADS, 4)
void altup_fused(const float* __restrict__ hs, const float* __restrict__ act,
                 const float* __restrict__ rnw, const float* __restrict__ mrw,
                 const float* __restrict__ pw, const float* __restrict__ cw,
                 const float* __restrict__ scale, float* __restrict__ out, int T)
{
    const int t = blockIdx.x;
    const int tid = threadIdx.x;
    const size_t row = (size_t)t * HDIM;
    const size_t plane = (size_t)T * HDIM;
    const v4f* hs0p = (const v4f*)(hs + row);
    const v4f* actp = (const v4f*)(act + row);
    const v4f* wp   = (const v4f*)rnw;
    const v4f* mrp  = (const v4f*)mrw;
    v4f x0v[VEC], av[VEC];
    float acc[10];
    #pragma unroll
    for (int k = 0; k < 10; ++k) acc[k] = 0.f;
    #pragma unroll
    for (int v = 0; v < VEC; ++v) {
        const int idx = tid + v * THREADS;
        const v4f x  = __builtin_nontemporal_load(hs0p + idx);
        const v4f a  = __builtin_nontemporal_load(actp + idx);
        const v4f ww = wp[idx];
        x0v[v] = x; av[v] = a;
        acc[0] += x.x*x.x + x.y*x.y + x.z*x.z + x.w*x.w;
        acc[5] += a.x*a.x + a.y*a.y + a.z*a.z + a.w*a.w;
        const float xwx = x.x*ww.x, xwy = x.y*ww.y, xwz = x.z*ww.z, xww = x.w*ww.w;
        const float awx = a.x*ww.x, awy = a.y*ww.y, awz = a.z*ww.z, aww = a.w*ww.w;
        #pragma unroll
        for (int n = 0; n < 4; ++n) {
            const v4f r = mrp[n * (HDIM/4) + idx];
            acc[1+n] += xwx*r.x + xwy*r.y + xwz*r.z + xww*r.w;
            acc[6+n] += awx*r.x + awy*r.y + awz*r.z + aww*r.w;
        }
    }
    const v4f* h1p = (const v4f*)(hs + plane + row);
    const v4f* h2p = (const v4f*)(hs + 2*plane + row);
    const v4f* h3p = (const v4f*)(hs + 3*plane + row);
    const v4f* scp = (const v4f*)scale;
    v4f x1v[VEC], x2v[VEC], x3v[VEC], scv[VEC];
    #pragma unroll
    for (int v = 0; v < VEC; ++v) {
        const int idx = tid + v * THREADS;
        x1v[v] = __builtin_nontemporal_load(h1p + idx);
        x2v[v] = __builtin_nontemporal_load(h2p + idx);
        x3v[v] = __builtin_nontemporal_load(h3p + idx);
        scv[v] = scp[idx];
    }
    __shared__ float part[THREADS/64][10];
    const int lane = tid & 63, wv = tid >> 6;
    #pragma unroll
    for (int k = 0; k < 10; ++k) {
        float s = acc[k];
        #pragma unroll
        for (int off = 32; off >= 1; off >>= 1) s += __shfl_down(s, off, 64);
        if (lane == 0) part[wv][k] = s;
    }
    __syncthreads();
    float tot[10];
    #pragma unroll
    for (int k = 0; k < 10; ++k)
        tot[k] = part[0][k] + part[1][k] + part[2][k] + part[3][k];
    const float invH = 1.0f / HDIM;
    const float rs0 = rsqrtf(tot[0] * invH + 1e-6f) * invH;
    const float rsA = rsqrtf(tot[5] * invH + 1e-6f) * invH;
    float m0[4], m2[4];
    #pragma unroll
    for (int n = 0; n < 4; ++n) {
        m0[n] = tanhf(tot[1+n] * rs0);
        m2[n] = tanhf(tot[6+n] * rsA);
    }
    float c[4][4], cc[4];
    #pragma unroll
    for (int j = 0; j < 4; ++j) {
        #pragma unroll
        for (int i = 0; i < 4; ++i) {
            const float* p = pw + (j*4 + i) * 4;
            c[j][i] = p[0]*m0[0] + p[1]*m0[1] + p[2]*m0[2] + p[3]*m0[3]
                    + (i == j ? 1.f : 0.f);
        }
        const float* q = cw + j*4;
        cc[j] = 1.f + q[0]*m2[0] + q[1]*m2[1] + q[2]*m2[2] + q[3]*m2[3];
    }
    float* o0 = out + row;
    float* o1 = out + plane + row;
    float* o2 = out + 2*plane + row;
    float* o3 = out + 3*plane + row;
    #pragma unroll
    for (int v = 0; v < VEC; ++v) {
        const int idx = tid + v * THREADS;
        const v4f x0 = x0v[v];
        const v4f a  = av[v];
        const v4f x1 = x1v[v];
        const v4f x2 = x2v[v];
        const v4f x3 = x3v[v];
        const v4f sc = scv[v];
        v4f r0, r1, r2, r3;
        #define COMP(f) { \
            const float p0 = c[0][0]*x0.f + c[0][1]*x1.f + c[0][2]*x2.f + c[0][3]*x3.f; \
            const float p1 = c[1][0]*x0.f + c[1][1]*x1.f + c[1][2]*x2.f + c[1][3]*x3.f; \
            const float p2 = c[2][0]*x0.f + c[2][1]*x1.f + c[2][2]*x2.f + c[2][3]*x3.f; \
            const float p3 = c[3][0]*x0.f + c[3][1]*x1.f + c[3][2]*x2.f + c[3][3]*x3.f; \
            const float inn = a.f - p0; \
            r0.f = (p0 + inn*cc[0]) * sc.f; \
            r1.f = (p1 + inn*cc[1]) * sc.f; \
            r2.f = (p2 + inn*cc[2]) * sc.f; \
            r3.f = (p3 + inn*cc[3]) * sc.f; }
        COMP(x) COMP(y) COMP(z) COMP(w)
        #undef COMP
        __builtin_nontemporal_store(r0, (v4f*)(o0) + idx);
        __builtin_nontemporal_store(r1, (v4f*)(o1) + idx);
        __builtin_nontemporal_store(r2, (v4f*)(o2) + idx);
        __builtin_nontemporal_store(r3, (v4f*)(o3) + idx);
    }
}

extern "C" void kernel_launch(void* const* d_in, const int* in_sizes, int n_in,
                              void* d_out, int out_size, void* d_ws, size_t ws_size,
                              hipStream_t stream) {
    const float* hs  = (const float*)d_in[0];  // hidden_states [4,B,S,H]
    const float* act = (const float*)d_in[1];  // activated [B,S,H]
    const float* rnw = (const float*)d_in[2];  // router_norm_weight [H]
    const float* mrw = (const float*)d_in[3];  // modality_router_w [4,H]
    const float* pw  = (const float*)d_in[4];  // prediction_w [16,4]
    const float* cw  = (const float*)d_in[5];  // correction_w [4,4]
    const float* sc  = (const float*)d_in[6];  // correct_output_scale [H]
    float* out = (float*)d_out;

    const int T = in_sizes[1] / HDIM;          // B*S tokens
    const size_t need = (size_t)T * COEF_STRIDE * sizeof(float);

    if (d_ws != nullptr && ws_size >= need) {
        float* coefs = (float*)d_ws;
        coef_kernel<<<T, THREADS, 0, stream>>>(hs, act, rnw, mrw, pw, cw, coefs, T);
        combine_kernel<<<T, THREADS, 0, stream>>>(hs, act, sc, coefs, out, T);
    } else {
        altup_fused<<<T, THREADS, 0, stream>>>(hs, act, rnw, mrw, pw, cw, sc, out, T);
    }
}

// Round 3
// 507.738 us; speedup vs baseline: 1.0186x; 1.0186x over previous
//
#include <hip/hip_runtime.h>
#include <math.h>

#define HDIM 2048
#define THREADS 256
#define VEC (HDIM / (THREADS * 4))  // 2 v4f per thread per row
#define MAXB 1024                   // persistent grid: 4 blocks/CU x 256 CU

typedef float v4f __attribute__((ext_vector_type(4)));

// Persistent fused kernel: each block owns a contiguous chunk of tokens and
// software-pipelines across them — while token t is in its reduce/coef/store
// phase, token t+1's hs0/act loads are already in flight. This keeps reads
// outstanding during the reduce bubble and the store burst (round-0's
// structure had a cold start + phase lockstep every token).
__global__ __launch_bounds__(THREADS, 4)
void altup_kernel(const float* __restrict__ hs,     // [4, T, H]
                  const float* __restrict__ act,    // [T, H]
                  const float* __restrict__ rnw,    // [H]
                  const float* __restrict__ mrw,    // [4, H]
                  const float* __restrict__ pw,     // [16, 4]
                  const float* __restrict__ cw,     // [4, 4]
                  const float* __restrict__ scale,  // [H]
                  float* __restrict__ out,          // [4, T, H]
                  int T, int chunk)
{
    const int tid = threadIdx.x;
    const int t0 = blockIdx.x * chunk;
    const int t1 = (t0 + chunk < T) ? (t0 + chunk) : T;
    if (t0 >= t1) return;

    const size_t plane = (size_t)T * HDIM;
    const v4f* wp  = (const v4f*)rnw;     // L2-resident weights
    const v4f* mrp = (const v4f*)mrw;
    const v4f* scp = (const v4f*)scale;

    __shared__ float part[THREADS/64][10];
    const int lane = tid & 63, wv = tid >> 6;

    // ---- prologue: first token's hs0/act ----
    v4f x0v[VEC], av[VEC];
    {
        const size_t row = (size_t)t0 * HDIM;
        const v4f* hs0p = (const v4f*)(hs + row);
        const v4f* actp = (const v4f*)(act + row);
        #pragma unroll
        for (int v = 0; v < VEC; ++v) {
            const int idx = tid + v * THREADS;
            x0v[v] = __builtin_nontemporal_load(hs0p + idx);
            av[v]  = __builtin_nontemporal_load(actp + idx);
        }
    }

    for (int t = t0; t < t1; ++t) {
        const size_t row = (size_t)t * HDIM;

        // ---- phase 1: per-thread partial reductions (inputs already in regs) ----
        float acc[10];  // [0]=ssq(hs0), [1..4]=dot(hs0*w,mrw[n]), [5]=ssq(act), [6..9]=dot(act*w,mrw[n])
        #pragma unroll
        for (int k = 0; k < 10; ++k) acc[k] = 0.f;

        #pragma unroll
        for (int v = 0; v < VEC; ++v) {
            const int idx = tid + v * THREADS;
            const v4f x  = x0v[v];
            const v4f a  = av[v];
            const v4f ww = wp[idx];
            acc[0] += x.x*x.x + x.y*x.y + x.z*x.z + x.w*x.w;
            acc[5] += a.x*a.x + a.y*a.y + a.z*a.z + a.w*a.w;
            const float xwx = x.x*ww.x, xwy = x.y*ww.y, xwz = x.z*ww.z, xww = x.w*ww.w;
            const float awx = a.x*ww.x, awy = a.y*ww.y, awz = a.z*ww.z, aww = a.w*ww.w;
            #pragma unroll
            for (int n = 0; n < 4; ++n) {
                const v4f r = mrp[n * (HDIM/4) + idx];
                acc[1+n] += xwx*r.x + xwy*r.y + xwz*r.z + xww*r.w;
                acc[6+n] += awx*r.x + awy*r.y + awz*r.z + aww*r.w;
            }
        }

        // ---- prefetch NEXT token's hs0/act: latency hides under the
        // reduce + coef math + combine/store phases below ----
        v4f nx0[VEC], na[VEC];
        if (t + 1 < t1) {
            const size_t nrow = row + HDIM;
            const v4f* hs0p = (const v4f*)(hs + nrow);
            const v4f* actp = (const v4f*)(act + nrow);
            #pragma unroll
            for (int v = 0; v < VEC; ++v) {
                const int idx = tid + v * THREADS;
                nx0[v] = __builtin_nontemporal_load(hs0p + idx);
                na[v]  = __builtin_nontemporal_load(actp + idx);
            }
        }

        // ---- wave shuffle reduce, then cross-wave via LDS ----
        #pragma unroll
        for (int k = 0; k < 10; ++k) {
            float s = acc[k];
            #pragma unroll
            for (int off = 32; off >= 1; off >>= 1) s += __shfl_down(s, off, 64);
            if (lane == 0) part[wv][k] = s;
        }
        __syncthreads();
        float tot[10];
        #pragma unroll
        for (int k = 0; k < 10; ++k)
            tot[k] = part[0][k] + part[1][k] + part[2][k] + part[3][k];
        __syncthreads();   // protect part[] reuse by next iteration

        // ---- tiny per-token math (redundant across threads) ----
        const float invH = 1.0f / HDIM;
        const float rs0 = rsqrtf(tot[0] * invH + 1e-6f) * invH;
        const float rsA = rsqrtf(tot[5] * invH + 1e-6f) * invH;
        float m0[4], m2[4];
        #pragma unroll
        for (int n = 0; n < 4; ++n) {
            m0[n] = tanhf(tot[1+n] * rs0);
            m2[n] = tanhf(tot[6+n] * rsA);
        }
        float c[4][4], cc[4];
        #pragma unroll
        for (int j = 0; j < 4; ++j) {
            #pragma unroll
            for (int i = 0; i < 4; ++i) {
                const float* p = pw + (j*4 + i) * 4;   // prediction_w[j*N+i, n]
                c[j][i] = p[0]*m0[0] + p[1]*m0[1] + p[2]*m0[2] + p[3]*m0[3]
                        + (i == j ? 1.f : 0.f);        // + identity (pred += hs[j])
            }
            const float* q = cw + j*4;                 // correction_w[j, n]
            cc[j] = 1.f + q[0]*m2[0] + q[1]*m2[1] + q[2]*m2[2] + q[3]*m2[3];
        }

        // ---- phase 2: stream hs1..3 + scale, combine, nontemporal-write ----
        const v4f* h1p = (const v4f*)(hs + plane + row);
        const v4f* h2p = (const v4f*)(hs + 2*plane + row);
        const v4f* h3p = (const v4f*)(hs + 3*plane + row);
        float* o0 = out + row;
        float* o1 = out + plane + row;
        float* o2 = out + 2*plane + row;
        float* o3 = out + 3*plane + row;

        #pragma unroll
        for (int v = 0; v < VEC; ++v) {
            const int idx = tid + v * THREADS;
            const v4f x1 = __builtin_nontemporal_load(h1p + idx);
            const v4f x2 = __builtin_nontemporal_load(h2p + idx);
            const v4f x3 = __builtin_nontemporal_load(h3p + idx);
            const v4f sc = scp[idx];
            const v4f x0 = x0v[v];
            const v4f a  = av[v];
            v4f r0, r1, r2, r3;
            #define COMP(f) { \
                const float p0 = c[0][0]*x0.f + c[0][1]*x1.f + c[0][2]*x2.f + c[0][3]*x3.f; \
                const float p1 = c[1][0]*x0.f + c[1][1]*x1.f + c[1][2]*x2.f + c[1][3]*x3.f; \
                const float p2 = c[2][0]*x0.f + c[2][1]*x1.f + c[2][2]*x2.f + c[2][3]*x3.f; \
                const float p3 = c[3][0]*x0.f + c[3][1]*x1.f + c[3][2]*x2.f + c[3][3]*x3.f; \
                const float inn = a.f - p0; \
                r0.f = (p0 + inn*cc[0]) * sc.f; \
                r1.f = (p1 + inn*cc[1]) * sc.f; \
                r2.f = (p2 + inn*cc[2]) * sc.f; \
                r3.f = (p3 + inn*cc[3]) * sc.f; }
            COMP(x) COMP(y) COMP(z) COMP(w)
            #undef COMP
            __builtin_nontemporal_store(r0, (v4f*)(o0) + idx);
            __builtin_nontemporal_store(r1, (v4f*)(o1) + idx);
            __builtin_nontemporal_store(r2, (v4f*)(o2) + idx);
            __builtin_nontemporal_store(r3, (v4f*)(o3) + idx);
        }

        // ---- rotate pipeline ----
        #pragma unroll
        for (int v = 0; v < VEC; ++v) { x0v[v] = nx0[v]; av[v] = na[v]; }
    }
}

extern "C" void kernel_launch(void* const* d_in, const int* in_sizes, int n_in,
                              void* d_out, int out_size, void* d_ws, size_t ws_size,
                              hipStream_t stream) {
    const float* hs  = (const float*)d_in[0];  // hidden_states [4,B,S,H]
    const float* act = (const float*)d_in[1];  // activated [B,S,H]
    const float* rnw = (const float*)d_in[2];  // router_norm_weight [H]
    const float* mrw = (const float*)d_in[3];  // modality_router_w [4,H]
    const float* pw  = (const float*)d_in[4];  // prediction_w [16,4]
    const float* cw  = (const float*)d_in[5];  // correction_w [4,4]
    const float* sc  = (const float*)d_in[6];  // correct_output_scale [H]
    float* out = (float*)d_out;

    const int T = in_sizes[1] / HDIM;          // B*S tokens
    int nb = (T < MAXB) ? T : MAXB;
    const int chunk = (T + nb - 1) / nb;       // tokens per block (contiguous)
    nb = (T + chunk - 1) / chunk;
    altup_kernel<<<nb, THREADS, 0, stream>>>(hs, act, rnw, mrw, pw, cw, sc, out, T, chunk);
}

// Round 4
// 472.682 us; speedup vs baseline: 1.0942x; 1.0742x over previous
//
#include <hip/hip_runtime.h>
#include <math.h>

#define HDIM 2048
#define THREADS 256
#define VEC (HDIM / (THREADS * 4))  // 2 float4-equivalents per thread per row

typedef float v4f __attribute__((ext_vector_type(4)));

__global__ __launch_bounds__(THREADS, 4)
void altup_kernel(const float* __restrict__ hs,     // [4, T, H]
                  const float* __restrict__ act,    // [T, H]
                  const float* __restrict__ rnw,    // [H]
                  const float* __restrict__ mrw,    // [4, H]
                  const float* __restrict__ pw,     // [16, 4]
                  const float* __restrict__ cw,     // [4, 4]
                  const float* __restrict__ scale,  // [H]
                  float* __restrict__ out,          // [4, T, H]
                  int T)
{
    const int t = blockIdx.x;
    const int tid = threadIdx.x;
    const size_t row = (size_t)t * HDIM;
    const size_t plane = (size_t)T * HDIM;

    const v4f* hs0p = (const v4f*)(hs + row);
    const v4f* actp = (const v4f*)(act + row);
    const v4f* wp   = (const v4f*)rnw;     // reused across all blocks -> cached
    const v4f* mrp  = (const v4f*)mrw;     // reused across all blocks -> cached

    // ---- phase 1: reductions for both modality() calls ----
    // Streamed rows (touch-once) use nontemporal loads to avoid L2 pollution.
    v4f x0v[VEC], av[VEC];
    float acc[10];  // [0]=ssq(hs0), [1..4]=dot(hs0*w,mrw[n]), [5]=ssq(act), [6..9]=dot(act*w,mrw[n])
    #pragma unroll
    for (int k = 0; k < 10; ++k) acc[k] = 0.f;

    #pragma unroll
    for (int v = 0; v < VEC; ++v) {
        const int idx = tid + v * THREADS;
        const v4f x  = __builtin_nontemporal_load(hs0p + idx);
        const v4f a  = __builtin_nontemporal_load(actp + idx);
        const v4f ww = wp[idx];
        x0v[v] = x; av[v] = a;
        acc[0] += x.x*x.x + x.y*x.y + x.z*x.z + x.w*x.w;
        acc[5] += a.x*a.x + a.y*a.y + a.z*a.z + a.w*a.w;
        const float xwx = x.x*ww.x, xwy = x.y*ww.y, xwz = x.z*ww.z, xww = x.w*ww.w;
        const float awx = a.x*ww.x, awy = a.y*ww.y, awz = a.z*ww.z, aww = a.w*ww.w;
        #pragma unroll
        for (int n = 0; n < 4; ++n) {
            const v4f r = mrp[n * (HDIM/4) + idx];
            acc[1+n] += xwx*r.x + xwy*r.y + xwz*r.z + xww*r.w;
            acc[6+n] += awx*r.x + awy*r.y + awz*r.z + aww*r.w;
        }
    }

    // ---- prefetch phase-2 streams BEFORE the reduction so their HBM
    // latency overlaps the shuffle/LDS reduction + tanh math ----
    const v4f* h1p = (const v4f*)(hs + plane + row);
    const v4f* h2p = (const v4f*)(hs + 2*plane + row);
    const v4f* h3p = (const v4f*)(hs + 3*plane + row);
    const v4f* scp = (const v4f*)scale;    // reused across all blocks -> cached
    v4f x1v[VEC], x2v[VEC], x3v[VEC], scv[VEC];
    #pragma unroll
    for (int v = 0; v < VEC; ++v) {
        const int idx = tid + v * THREADS;
        x1v[v] = __builtin_nontemporal_load(h1p + idx);
        x2v[v] = __builtin_nontemporal_load(h2p + idx);
        x3v[v] = __builtin_nontemporal_load(h3p + idx);
        scv[v] = scp[idx];
    }

    // ---- wave shuffle reduce, then cross-wave via LDS ----
    __shared__ float part[THREADS/64][10];
    const int lane = tid & 63, wv = tid >> 6;
    #pragma unroll
    for (int k = 0; k < 10; ++k) {
        float s = acc[k];
        #pragma unroll
        for (int off = 32; off >= 1; off >>= 1) s += __shfl_down(s, off, 64);
        if (lane == 0) part[wv][k] = s;
    }
    __syncthreads();
    float tot[10];
    #pragma unroll
    for (int k = 0; k < 10; ++k)
        tot[k] = part[0][k] + part[1][k] + part[2][k] + part[3][k];

    // ---- tiny per-token math (computed redundantly by all threads) ----
    const float invH = 1.0f / HDIM;
    const float rs0 = rsqrtf(tot[0] * invH + 1e-6f) * invH;
    const float rsA = rsqrtf(tot[5] * invH + 1e-6f) * invH;
    float m0[4], m2[4];
    #pragma unroll
    for (int n = 0; n < 4; ++n) {
        m0[n] = tanhf(tot[1+n] * rs0);
        m2[n] = tanhf(tot[6+n] * rsA);
    }
    float c[4][4], cc[4];
    #pragma unroll
    for (int j = 0; j < 4; ++j) {
        #pragma unroll
        for (int i = 0; i < 4; ++i) {
            const float* p = pw + (j*4 + i) * 4;   // prediction_w[j*N+i, n]
            c[j][i] = p[0]*m0[0] + p[1]*m0[1] + p[2]*m0[2] + p[3]*m0[3]
                    + (i == j ? 1.f : 0.f);        // + identity (pred += hs[j])
        }
        const float* q = cw + j*4;                 // correction_w[j, n]
        cc[j] = 1.f + q[0]*m2[0] + q[1]*m2[1] + q[2]*m2[2] + q[3]*m2[3];
    }

    // ---- phase 2: combine, nontemporal-write 4 output planes ----
    float* o0 = out + row;
    float* o1 = out + plane + row;
    float* o2 = out + 2*plane + row;
    float* o3 = out + 3*plane + row;

    #pragma unroll
    for (int v = 0; v < VEC; ++v) {
        const int idx = tid + v * THREADS;
        const v4f x0 = x0v[v];
        const v4f a  = av[v];
        const v4f x1 = x1v[v];
        const v4f x2 = x2v[v];
        const v4f x3 = x3v[v];
        const v4f sc = scv[v];
        v4f r0, r1, r2, r3;
        #define COMP(f) { \
            const float p0 = c[0][0]*x0.f + c[0][1]*x1.f + c[0][2]*x2.f + c[0][3]*x3.f; \
            const float p1 = c[1][0]*x0.f + c[1][1]*x1.f + c[1][2]*x2.f + c[1][3]*x3.f; \
            const float p2 = c[2][0]*x0.f + c[2][1]*x1.f + c[2][2]*x2.f + c[2][3]*x3.f; \
            const float p3 = c[3][0]*x0.f + c[3][1]*x1.f + c[3][2]*x2.f + c[3][3]*x3.f; \
            const float inn = a.f - p0; \
            r0.f = (p0 + inn*cc[0]) * sc.f; \
            r1.f = (p1 + inn*cc[1]) * sc.f; \
            r2.f = (p2 + inn*cc[2]) * sc.f; \
            r3.f = (p3 + inn*cc[3]) * sc.f; }
        COMP(x) COMP(y) COMP(z) COMP(w)
        #undef COMP
        __builtin_nontemporal_store(r0, (v4f*)(o0) + idx);
        __builtin_nontemporal_store(r1, (v4f*)(o1) + idx);
        __builtin_nontemporal_store(r2, (v4f*)(o2) + idx);
        __builtin_nontemporal_store(r3, (v4f*)(o3) + idx);
    }
}

extern "C" void kernel_launch(void* const* d_in, const int* in_sizes, int n_in,
                              void* d_out, int out_size, void* d_ws, size_t ws_size,
                              hipStream_t stream) {
    const float* hs  = (const float*)d_in[0];  // hidden_states [4,B,S,H]
    const float* act = (const float*)d_in[1];  // activated [B,S,H]
    const float* rnw = (const float*)d_in[2];  // router_norm_weight [H]
    const float* mrw = (const float*)d_in[3];  // modality_router_w [4,H]
    const float* pw  = (const float*)d_in[4];  // prediction_w [16,4]
    const float* cw  = (const float*)d_in[5];  // correction_w [4,4]
    const float* sc  = (const float*)d_in[6];  // correct_output_scale [H]
    float* out = (float*)d_out;

    const int T = in_sizes[1] / HDIM;          // B*S tokens
    altup_kernel<<<T, THREADS, 0, stream>>>(hs, act, rnw, mrw, pw, cw, sc, out, T);
}